// Round 13
// baseline (248.517 us; speedup 1.0000x reference)
//
#include <hip/hip_runtime.h>
#include <math.h>

// ---- problem constants ----
#define NT   16384
#define HD   4096
#define NE   64
#define TOPK 8

// ---- d_out layout: FLOAT32 elements (proven rounds 5/7/8/9/12) ----
#define L_OFF 0
#define W_OFF (NT * NE)                  // 1048576
#define I_OFF (W_OFF + NT * TOPK)        // 1179648
#define M_OFF (I_OFF + NT * TOPK)        // 1310720 ; mask = NE*TOPK*NT floats

#define BK 64                            // K-chunk
#define PD 65                            // LDS row stride (floats)

typedef __attribute__((ext_vector_type(4))) float f4;

// ---- kernel A: zero the fp32 mask region ----
__global__ __launch_bounds__(256) void kz_mask(f4* __restrict__ p, int n4) {
  f4 z = {0.f, 0.f, 0.f, 0.f};
  for (int i = blockIdx.x * 256 + threadIdx.x; i < n4; i += gridDim.x * 256) p[i] = z;
}

// ---- kernel B: fp32 VALU GEMM, 4x4 register tile per thread ----
// block 128 thr (2 waves) = tile 32 tokens x 64 experts; grid NT/32 = 512.
// thread (tr,tc): tokens tr*4..+3, experts tc*4..+3 -> 16 outputs, 64 fma / 8 LDS
// reads per st-step (vs 32/9 in round 12: 3.5x fewer LDS instructions per fma).
// x,w double-buffered in LDS; 1 barrier/chunk; chunk c+2 loads issued during c.
// Per-(t,e) accumulation BITWISE-IDENTICAL to rounds 5-12: 4 component chains
// (k mod 4), k ascending, final ((c0+c1)+c2)+c3 + bias.
__global__ __launch_bounds__(128) void k_gemm(const float* __restrict__ x,
                                              const float* __restrict__ w,
                                              const float* __restrict__ bias,
                                              float* __restrict__ out) {
  __shared__ float xs[2][32 * PD];       // 2 x 8.3 KB
  __shared__ float ws[2][64 * PD];       // 2 x 16.6 KB  (total 49.9 KB)

  const int tid = threadIdx.x;
  const int tr  = tid >> 4;              // 0..7  : token group
  const int tc  = tid & 15;              // 0..15 : expert group
  const int su  = tid & 15;              // staging 16B-unit
  const int tok0 = blockIdx.x * 32;

  f4 acc[4][4];                          // [token i][expert s] -> 4 chains
#pragma unroll
  for (int i = 0; i < 4; ++i)
#pragma unroll
    for (int s = 0; s < 4; ++s) acc[i][s] = (f4){0.f, 0.f, 0.f, 0.f};

  // staging: x rows tr+8p (p<4), w rows tr+8p (p<8), unit su
  const float* xg = x + (size_t)(tok0 + tr) * HD + su * 4;
  const float* wg = w + (size_t)tr * HD + su * 4;

  f4 px[4], pw[8];

  // prologue: chunk0 -> regs -> buf0; chunk1 -> regs (in flight)
#pragma unroll
  for (int p = 0; p < 4; ++p) px[p] = *(const f4*)(xg + (size_t)(8 * p) * HD);
#pragma unroll
  for (int p = 0; p < 8; ++p) pw[p] = *(const f4*)(wg + (size_t)(8 * p) * HD);
#pragma unroll
  for (int p = 0; p < 4; ++p) *(f4*)(&xs[0][(tr + 8 * p) * PD + su * 4]) = px[p];
#pragma unroll
  for (int p = 0; p < 8; ++p) *(f4*)(&ws[0][(tr + 8 * p) * PD + su * 4]) = pw[p];
#pragma unroll
  for (int p = 0; p < 4; ++p) px[p] = *(const f4*)(xg + (size_t)(8 * p) * HD + BK);
#pragma unroll
  for (int p = 0; p < 8; ++p) pw[p] = *(const f4*)(wg + (size_t)(8 * p) * HD + BK);
  __syncthreads();

  for (int c = 0; c < HD / BK; ++c) {
    const int b = c & 1;
    // stage chunk c+1 (regs landed) into the other buffer
    if (c + 1 < HD / BK) {
#pragma unroll
      for (int p = 0; p < 4; ++p) *(f4*)(&xs[b ^ 1][(tr + 8 * p) * PD + su * 4]) = px[p];
#pragma unroll
      for (int p = 0; p < 8; ++p) *(f4*)(&ws[b ^ 1][(tr + 8 * p) * PD + su * 4]) = pw[p];
    }
    // issue chunk c+2 global loads; they land under this chunk's compute
    if (c + 2 < HD / BK) {
      const int kc = (c + 2) * BK;
#pragma unroll
      for (int p = 0; p < 4; ++p) px[p] = *(const f4*)(xg + (size_t)(8 * p) * HD + kc);
#pragma unroll
      for (int p = 0; p < 8; ++p) pw[p] = *(const f4*)(wg + (size_t)(8 * p) * HD + kc);
    }

    // compute chunk c: per st: 4 x reads (16-lane multicast) + 4 w reads (2-way) + 64 fma
#pragma unroll
    for (int st = 0; st < 16; ++st) {
      const int k0 = st * 4;
      f4 xv[4], wf[4];
#pragma unroll
      for (int i = 0; i < 4; ++i) xv[i] = *(const f4*)(&xs[b][(tr * 4 + i) * PD + k0]);
#pragma unroll
      for (int s = 0; s < 4; ++s) wf[s] = *(const f4*)(&ws[b][(tc * 4 + s) * PD + k0]);
#pragma unroll
      for (int i = 0; i < 4; ++i)
#pragma unroll
        for (int s = 0; s < 4; ++s)
#pragma unroll
          for (int j = 0; j < 4; ++j)
            acc[i][s][j] = fmaf(xv[i][j], wf[s][j], acc[i][s][j]);
    }
    __syncthreads();
  }

  // epilogue: same final-sum order as rounds 5-12; f4 store per token row
  const f4 bv = *(const f4*)(bias + tc * 4);
#pragma unroll
  for (int i = 0; i < 4; ++i) {
    const int row = tok0 + tr * 4 + i;
    f4 r;
#pragma unroll
    for (int s = 0; s < 4; ++s)
      r[s] = acc[i][s][0] + acc[i][s][1] + acc[i][s][2] + acc[i][s][3] + bv[s];
    *(f4*)(out + L_OFF + (size_t)row * NE + tc * 4) = r;
  }
}

// ---- kernel C: top-8 from stored fp32 logits (rounds 5-12 verbatim selection) ----
__global__ __launch_bounds__(256) void k_topk(float* __restrict__ out) {
  const int lane = threadIdx.x & 63;            // lane == expert
  const int wv   = threadIdx.x >> 6;
  const int t    = blockIdx.x * 4 + wv;

  float v = out[L_OFF + (size_t)t * NE + lane];

  // rank = #{e : v_e > v or (v_e == v and e < lane)}  (stable, lax.top_k order)
  int rank = 0;
  for (int e = 0; e < NE; ++e) {
    float ve = __shfl(v, e);
    rank += (ve > v) || (ve == v && e < lane);
  }

  // weights = softmax over the selected 8 (global Z cancels in renormalization)
  float m0 = v;
#pragma unroll
  for (int o = 32; o; o >>= 1) m0 = fmaxf(m0, __shfl_xor(m0, o));
  float ev = (rank < TOPK) ? expf(v - m0) : 0.f;
  float s = ev;
#pragma unroll
  for (int o = 32; o; o >>= 1) s += __shfl_xor(s, o);

  if (rank < TOPK) {
    out[W_OFF + (size_t)t * TOPK + rank] = ev / s;
    out[I_OFF + (size_t)t * TOPK + rank] = (float)lane;                  // exact (<=63)
    out[M_OFF + ((size_t)lane * TOPK + rank) * NT + t] = 1.0f;           // mask one-hot
  }
}

extern "C" void kernel_launch(void* const* d_in, const int* in_sizes, int n_in,
                              void* d_out, int out_size, void* d_ws, size_t ws_size,
                              hipStream_t stream) {
  const float* x  = (const float*)d_in[0];
  const float* gw = (const float*)d_in[1];
  const float* gb = (const float*)d_in[2];
  float* out = (float*)d_out;

  kz_mask<<<2048, 256, 0, stream>>>((f4*)(out + M_OFF), (NE * TOPK * NT) / 4);
  k_gemm <<<NT / 32, 128, 0, stream>>>(x, gw, gb, out);
  k_topk <<<NT / 4, 256, 0, stream>>>(out);
}